// Round 10
// baseline (237.803 us; speedup 1.0000x reference)
//
#include <hip/hip_runtime.h>
#include <stdint.h>

using f16 = _Float16;

typedef _Float16 f16x8 __attribute__((ext_vector_type(8)));
typedef float f32x4 __attribute__((ext_vector_type(4)));

#define LOG2E 1.44269504088896340736f

__device__ __forceinline__ f16 f2h(float f) { return (f16)f; }  // RNE

#if __has_builtin(__builtin_amdgcn_exp2f)
__device__ __forceinline__ float fexp2(float x) { return __builtin_amdgcn_exp2f(x); }
#else
__device__ __forceinline__ float fexp2(float x) { return exp2f(x); }
#endif

__device__ __forceinline__ f16x8 cvt8(const float* p) {
  const float4 a = *(const float4*)p;
  const float4 b = *(const float4*)(p + 4);
  f16x8 r;
  r[0] = (f16)a.x; r[1] = (f16)a.y; r[2] = (f16)a.z; r[3] = (f16)a.w;
  r[4] = (f16)b.x; r[5] = (f16)b.y; r[6] = (f16)b.z; r[7] = (f16)b.w;
  return r;
}

// B=4, C=64, N=4096.  Global in/out tensors FP32; internal tensor-core path FP16.
// ws layout (bytes):
//   0        qa  f16 [4][4096][64]  (2 MB)   q * log2e, position-major
//   2 MB     ka  f16 [4][4096][64]  (2 MB)
//   4 MB     va  f16 [4][64][4096]  (2 MB)   channel-major
//   6 MB     y0  f32 [4][64][4096]  (4 MB)   gamma*attn_out, pre-BN
//   10 MB    stats: gs1[64] | gs2[64]  (contiguous 128 floats, zeroed by pre)

// ---------------------------------------------------------------------------
// pre: conv1d q/k over channels, v = vw@x+vb via MFMA.
// grid 512 = (b, n-tile of 32) -> 2 blocks/CU (r9 residual: pre was 1/CU,
// latency-walled). Block 0 also zeroes gs1/gs2 (replaces memset node).
// ---------------------------------------------------------------------------
__global__ __launch_bounds__(256, 2) void pam_pre(
    const float* __restrict__ x, const float* __restrict__ qw,
    const float* __restrict__ kw, const float* __restrict__ vw,
    const float* __restrict__ vb,
    f16* __restrict__ qa, f16* __restrict__ ka, f16* __restrict__ va,
    float* __restrict__ gz)
{
  __shared__ alignas(16) f16 xt[32 * 72];   // xt[n][c] f16, row stride 72 elems
  const int tid = threadIdx.x;
  const int b = blockIdx.x >> 7;
  const int n0 = (blockIdx.x & 127) << 5;
  const int lane = tid & 63;
  const int wv = tid >> 6;
  const int quad = lane >> 4, l15 = lane & 15;

  if (blockIdx.x == 0 && tid < 128) gz[tid] = 0.f;   // gs1|gs2 zero-init

  // stage x[b][c][n0:+32] (fp32) transposed into xt[n][c] (f16)
  {
    const int c = tid >> 2;
    const int j0 = (tid & 3) << 3;
    const float* xp = x + ((size_t)(b * 64 + c) << 12) + n0 + j0;
    const float4 v0 = *(const float4*)xp;
    const float4 v1 = *(const float4*)(xp + 4);
    xt[(j0 + 0) * 72 + c] = f2h(v0.x);
    xt[(j0 + 1) * 72 + c] = f2h(v0.y);
    xt[(j0 + 2) * 72 + c] = f2h(v0.z);
    xt[(j0 + 3) * 72 + c] = f2h(v0.w);
    xt[(j0 + 4) * 72 + c] = f2h(v1.x);
    xt[(j0 + 5) * 72 + c] = f2h(v1.y);
    xt[(j0 + 6) * 72 + c] = f2h(v1.z);
    xt[(j0 + 7) * 72 + c] = f2h(v1.w);
  }
  __syncthreads();

  // conv along channel axis (SAME, zero pad), fp32 math on f16-rounded x
  const float qw0 = qw[0], qw1 = qw[1], qw2 = qw[2];
  const float kw0 = kw[0], kw1 = kw[1], kw2 = kw[2];
  for (int p = 0; p < 8; ++p) {
    const int c = lane;
    const int jr = (p << 2) + wv;
    const int n = n0 + jr;
    const float xm = (c > 0) ? (float)xt[jr * 72 + c - 1] : 0.f;
    const float x0 = (float)xt[jr * 72 + c];
    const float xp = (c < 63) ? (float)xt[jr * 72 + c + 1] : 0.f;
    const float qv = (qw0 * xm + qw1 * x0 + qw2 * xp) * LOG2E;  // log2-domain
    const float kv = kw0 * xm + kw1 * x0 + kw2 * xp;
    const size_t off = ((size_t)((b << 12) + n) << 6) + c;
    qa[off] = f2h(qv);
    ka[off] = f2h(kv);
  }

  // v[b][c][n] = vw @ x + vb via mfma 16x16x32 (wave wv -> c rows [16wv,+16))
  {
    const f16x8 a0 = cvt8(vw + (wv * 16 + l15) * 64 + quad * 8);
    const f16x8 a1 = cvt8(vw + (wv * 16 + l15) * 64 + quad * 8 + 32);
    f32x4 acc[2];
    for (int st = 0; st < 2; ++st) {
      const f16x8 b0 = *(const f16x8*)&xt[(st * 16 + l15) * 72 + quad * 8];
      const f16x8 b1 = *(const f16x8*)&xt[(st * 16 + l15) * 72 + quad * 8 + 32];
      f32x4 z = {0.f, 0.f, 0.f, 0.f};
      z = __builtin_amdgcn_mfma_f32_16x16x32_f16(a0, b0, z, 0, 0, 0);
      acc[st] = __builtin_amdgcn_mfma_f32_16x16x32_f16(a1, b1, z, 0, 0, 0);
    }
    const int cobase = wv * 16 + quad * 4;
    for (int st = 0; st < 2; ++st)
      for (int r = 0; r < 4; ++r) {
        const int co = cobase + r;
        const float val = acc[st][r] + vb[co];
        va[((size_t)(b * 64 + co) << 12) + n0 + st * 16 + l15] = f2h(val);
      }
  }
}

// ---------------------------------------------------------------------------
// attention: block = (b, 32 queries), 512 threads = 8 waves key-split
// (32 keys/wave over 256-key tiles, 16 iters). SINGLE PASS, online softmax,
// 1-deep register prefetch. Grid 512 -> 2 blocks/CU = 16 waves/CU = 4/SIMD
// (r9: 2/SIMD was the latency wall; same K/V traffic as r9 at 2x the TLP).
// m/l in S^T layout (query=l15); lpart per-lane partial, cross-quad reduced
// before publish. alpha redistributed to C-layout via shfl. Cross-wave merge
// m-aware over 8 waves. Per-block phase rotation (anti-convoy).
// ---------------------------------------------------------------------------
__global__ __launch_bounds__(512, 4) void pam_attn(
    const f16* __restrict__ qa, const f16* __restrict__ ka,
    const f16* __restrict__ va, const float* __restrict__ gam,
    float* __restrict__ y0, float* __restrict__ gs1, float* __restrict__ gs2)
{
  __shared__ alignas(16) f16 pbuf[8][32 * 32];  // per-wave P, 64B rows, swizzled
  __shared__ float ldsO[32 * 65];
  __shared__ float ldsL[8][32];
  __shared__ float ldsM[8][32];
  __shared__ float ldsMg[32];
  __shared__ float ldsInv[32];

  const int tid = threadIdx.x;
  const int wv = tid >> 6, lane = tid & 63;
  const int quad = lane >> 4, l15 = lane & 15;
  const int b = blockIdx.x & 3;
  const int qt_idx = blockIdx.x >> 2;          // 0..127
  const int qb0 = qt_idx << 5;
  const int phase = qt_idx & 15;               // anti-convoy rotation (16 tiles)

  for (int i = tid; i < 32 * 65; i += 512) ldsO[i] = 0.f;

  const int bn = b << 12;
  f16x8 bq[2][2];
  for (int qt = 0; qt < 2; ++qt) {
    const int q = qb0 + qt * 16 + l15;
    const f16* qp = qa + ((size_t)(bn + q) << 6) + quad * 8;
    bq[qt][0] = *(const f16x8*)qp;
    bq[qt][1] = *(const f16x8*)(qp + 32);
  }

  f32x4 o[2][4] = {};
  float m[2] = {-1e30f, -1e30f};
  float lpart[2] = {0.f, 0.f};
  f16* pb = pbuf[wv];

  // preload iteration 0 K/V fragments (256-key tiles, wave owns 32)
  f16x8 ak[2][2], bv[4];
  {
    const int kb = (phase << 8) + wv * 32;
    for (int mt = 0; mt < 2; ++mt) {
      const f16* kp = ka + ((size_t)(bn + kb + mt * 16 + l15) << 6) + quad * 8;
      ak[mt][0] = *(const f16x8*)kp;
      ak[mt][1] = *(const f16x8*)(kp + 32);
    }
    for (int ct = 0; ct < 4; ++ct)
      bv[ct] = *(const f16x8*)(va + ((size_t)(b * 64 + ct * 16 + l15) << 12) + kb + quad * 8);
  }

#pragma unroll 1
  for (int kt = 0; kt < 16; ++kt) {
    // prefetch next iteration's K/V into separate regs (wraps at 16)
    f16x8 akn[2][2], bvn[4];
    {
      const int kb2 = ((((kt + 1) + phase) & 15) << 8) + wv * 32;
      for (int mt = 0; mt < 2; ++mt) {
        const f16* kp = ka + ((size_t)(bn + kb2 + mt * 16 + l15) << 6) + quad * 8;
        akn[mt][0] = *(const f16x8*)kp;
        akn[mt][1] = *(const f16x8*)(kp + 32);
      }
      for (int ct = 0; ct < 4; ++ct)
        bvn[ct] = *(const f16x8*)(va + ((size_t)(b * 64 + ct * 16 + l15) << 12) + kb2 + quad * 8);
    }

    // S^T = K_slice * Q^T (C=0); online max/rescale; P -> LDS; PV
    for (int qt = 0; qt < 2; ++qt) {
      f32x4 s[2];
      for (int mt = 0; mt < 2; ++mt) {
        f32x4 z = {0.f, 0.f, 0.f, 0.f};
        z = __builtin_amdgcn_mfma_f32_16x16x32_f16(ak[mt][0], bq[qt][0], z, 0, 0, 0);
        s[mt] = __builtin_amdgcn_mfma_f32_16x16x32_f16(ak[mt][1], bq[qt][1], z, 0, 0, 0);
      }
      // tile max for this query (col=l15) across this wave's 32 keys
      float tmax = fmaxf(fmaxf(fmaxf(s[0][0], s[0][1]), fmaxf(s[0][2], s[0][3])),
                         fmaxf(fmaxf(s[1][0], s[1][1]), fmaxf(s[1][2], s[1][3])));
      tmax = fmaxf(tmax, __shfl_xor(tmax, 16, 64));
      tmax = fmaxf(tmax, __shfl_xor(tmax, 32, 64));
      const float mnew = fmaxf(m[qt], tmax);
      const float alpha = fexp2(m[qt] - mnew);   // (l15 = query) layout, quad-uniform
      m[qt] = mnew;

      // P = exp2(S - mnew); update per-lane partial l; pack -> LDS (swizzled)
      const int rowq = qt * 16 + l15;
      char* rowp = (char*)pb + rowq * 64;
      const int sw = rowq & 3;
      float tsum = 0.f;
      for (int mt = 0; mt < 2; ++mt) {
        const float p0 = fexp2(s[mt][0] - mnew);
        const float p1 = fexp2(s[mt][1] - mnew);
        const float p2 = fexp2(s[mt][2] - mnew);
        const float p3 = fexp2(s[mt][3] - mnew);
        tsum += (p0 + p1) + (p2 + p3);
        union { f16 h[4]; uint2 u; } pk;
        pk.h[0] = f2h(p0); pk.h[1] = f2h(p1);
        pk.h[2] = f2h(p2); pk.h[3] = f2h(p3);
        const int cc = (2 * mt + (quad >> 1)) ^ sw;
        *(uint2*)(rowp + cc * 16 + (quad & 1) * 8) = pk.u;
      }
      lpart[qt] = lpart[qt] * alpha + tsum;   // per-lane partial (8 keys/lane)

      // rescale o: o-queries are quad*4+r -> fetch alpha from lane (quad<<4)|(quad*4+r)
      const int srcbase = (lane & 48) + ((lane >> 4) << 2);
      for (int r = 0; r < 4; ++r) {
        const float ar = __shfl(alpha, srcbase + r, 64);
        for (int ct = 0; ct < 4; ++ct) o[qt][ct][r] *= ar;
      }
    }
    __builtin_amdgcn_s_waitcnt(0xC07F);  // lgkmcnt(0): per-wave P writes visible

    // O += P * V
    for (int qt = 0; qt < 2; ++qt) {
      const int rowq = qt * 16 + l15;
      const f16x8 ap =
          *(const f16x8*)((const char*)pb + rowq * 64 + ((quad ^ (rowq & 3)) << 4));
      for (int ct = 0; ct < 4; ++ct)
        o[qt][ct] = __builtin_amdgcn_mfma_f32_16x16x32_f16(ap, bv[ct], o[qt][ct], 0, 0, 0);
    }

    for (int mt = 0; mt < 2; ++mt) { ak[mt][0] = akn[mt][0]; ak[mt][1] = akn[mt][1]; }
    for (int ct = 0; ct < 4; ++ct) bv[ct] = bvn[ct];
  }

  // publish per-wave online state: m quad-uniform; lpart reduced across quads
  for (int qt = 0; qt < 2; ++qt) {
    float v = lpart[qt];
    v += __shfl_xor(v, 16, 64);
    v += __shfl_xor(v, 32, 64);
    if (quad == 0) {
      ldsM[wv][qt * 16 + l15] = m[qt];
      ldsL[wv][qt * 16 + l15] = v;
    }
  }
  __syncthreads();  // ldsM/ldsL published; ldsO zero-init complete

  // global (per-block) max + denom per query
  if (tid < 32) {
    const int q = tid;
    float M = ldsM[0][q];
    for (int w = 1; w < 8; ++w) M = fmaxf(M, ldsM[w][q]);
    float lt = 0.f;
    for (int w = 0; w < 8; ++w) lt += ldsL[w][q] * fexp2(ldsM[w][q] - M);
    ldsMg[q] = M;
    ldsInv[q] = 1.f / lt;
  }
  __syncthreads();

  // m-aware merge of partial O across the 8 key-split waves
  for (int qt = 0; qt < 2; ++qt) {
    for (int r = 0; r < 4; ++r) {
      const int q = qt * 16 + quad * 4 + r;
      const float sc = fexp2(ldsM[wv][q] - ldsMg[q]);
      for (int ct = 0; ct < 4; ++ct)
        atomicAdd(&ldsO[q * 65 + ct * 16 + l15], o[qt][ct][r] * sc);
    }
  }
  __syncthreads();

  // epilogue: y0[b][c][n] = gamma * O / l ; BN partial sums
  // thread -> (c = tid>>3, 4 consecutive q starting at (tid&7)*4)
  const float g = gam[0];
  {
    const int c = tid >> 3;
    const int q0 = (tid & 7) << 2;
    float4 v4;
    float* vp = &v4.x;
    float s1 = 0.f, s2 = 0.f;
    for (int r = 0; r < 4; ++r) {
      const float val = g * ldsO[(q0 + r) * 65 + c] * ldsInv[q0 + r];
      vp[r] = val; s1 += val; s2 += val * val;
    }
    *(float4*)(y0 + ((size_t)(b * 64 + c) << 12) + qb0 + q0) = v4;
    s1 += __shfl_xor(s1, 1, 64);
    s2 += __shfl_xor(s2, 1, 64);
    s1 += __shfl_xor(s1, 2, 64);
    s2 += __shfl_xor(s2, 2, 64);
    s1 += __shfl_xor(s1, 4, 64);
    s2 += __shfl_xor(s2, 4, 64);
    if ((tid & 7) == 0) {
      atomicAdd(&gs1[c], s1);
      atomicAdd(&gs2[c], s2);
    }
  }
}

// ---------------------------------------------------------------------------
// apply: BN(scale/shift recomputed per block from gs1/gs2) + residual.
// (stats kernel folded in -> one fewer graph node.)
// ---------------------------------------------------------------------------
__global__ __launch_bounds__(256, 4) void pam_apply(
    const float* __restrict__ y0, const float* __restrict__ x,
    const float* __restrict__ gs1, const float* __restrict__ gs2,
    const float* __restrict__ bnw, const float* __restrict__ bnb,
    float* __restrict__ out)
{
  const int i = (blockIdx.x * 256 + threadIdx.x) << 2;   // 4 elems/thread
  const int c = (i >> 12) & 63;
  const float inv_n = 1.f / 16384.f;
  const float mean = gs1[c] * inv_n;
  const float var = fmaxf(gs2[c] * inv_n - mean * mean, 0.f);
  const float sc = bnw[c] * rsqrtf(var + 1e-5f);
  const float sh = bnb[c] - mean * sc;
  const float4 y = *(const float4*)(y0 + i);
  const float4 xv = *(const float4*)(x + i);
  float4 r;
  r.x = y.x * sc + sh + xv.x;
  r.y = y.y * sc + sh + xv.y;
  r.z = y.z * sc + sh + xv.z;
  r.w = y.w * sc + sh + xv.w;
  *(float4*)(out + i) = r;
}

// ---------------------------------------------------------------------------
extern "C" void kernel_launch(void* const* d_in, const int* in_sizes, int n_in,
                              void* d_out, int out_size, void* d_ws, size_t ws_size,
                              hipStream_t stream)
{
  (void)in_sizes; (void)n_in; (void)out_size; (void)ws_size;
  const float* x   = (const float*)d_in[0];
  const float* qw  = (const float*)d_in[1];
  const float* kw  = (const float*)d_in[2];
  const float* vw  = (const float*)d_in[3];
  const float* vb  = (const float*)d_in[4];
  const float* gam = (const float*)d_in[5];
  const float* bnw = (const float*)d_in[6];
  const float* bnb = (const float*)d_in[7];

  char* ws = (char*)d_ws;
  f16*   qa  = (f16*)(ws);
  f16*   ka  = (f16*)(ws + (2u << 20));
  f16*   va  = (f16*)(ws + (4u << 20));
  float* y0  = (float*)(ws + (6u << 20));
  float* gs1 = (float*)(ws + (10u << 20));          // 64 floats
  float* gs2 = (float*)(ws + (10u << 20) + 256);    // 64 floats (contiguous)

  pam_pre  <<<512, 256, 0, stream>>>(x, qw, kw, vw, vb, qa, ka, va, gs1);
  pam_attn <<<512, 512, 0, stream>>>(qa, ka, va, gam, y0, gs1, gs2);
  pam_apply<<<1024, 256, 0, stream>>>(y0, x, gs1, gs2, bnw, bnb, (float*)d_out);
}

// Round 11
// 203.042 us; speedup vs baseline: 1.1712x; 1.1712x over previous
//
#include <hip/hip_runtime.h>
#include <stdint.h>

using f16 = _Float16;

typedef _Float16 f16x8 __attribute__((ext_vector_type(8)));
typedef float f32x4 __attribute__((ext_vector_type(4)));

#define LOG2E 1.44269504088896340736f

__device__ __forceinline__ f16 f2h(float f) { return (f16)f; }  // RNE

#if __has_builtin(__builtin_amdgcn_exp2f)
__device__ __forceinline__ float fexp2(float x) { return __builtin_amdgcn_exp2f(x); }
#else
__device__ __forceinline__ float fexp2(float x) { return exp2f(x); }
#endif

__device__ __forceinline__ f16x8 cvt8(const float* p) {
  const float4 a = *(const float4*)p;
  const float4 b = *(const float4*)(p + 4);
  f16x8 r;
  r[0] = (f16)a.x; r[1] = (f16)a.y; r[2] = (f16)a.z; r[3] = (f16)a.w;
  r[4] = (f16)b.x; r[5] = (f16)b.y; r[6] = (f16)b.z; r[7] = (f16)b.w;
  return r;
}

// B=4, C=64, N=4096.  Global in/out tensors FP32; internal tensor-core path FP16.
// ws layout (bytes):
//   0        qa  f16 [4][4096][64]  (2 MB)   q * log2e, position-major
//   2 MB     ka  f16 [4][4096][64]  (2 MB)
//   4 MB     va  f16 [4][64][4096]  (2 MB)   channel-major
//   6 MB     y0  f32 [4][64][4096]  (4 MB)   gamma*attn_out, pre-BN
//   10 MB    stats: gs1[64] | gs2[64]  (contiguous 128 floats, zeroed by pre)

// ---------------------------------------------------------------------------
// pre: conv1d q/k over channels, v = vw@x+vb via MFMA.
// grid 512 = (b, n-tile of 32) -> 2 blocks/CU. Block 0 zeroes gs1/gs2.
// ---------------------------------------------------------------------------
__global__ __launch_bounds__(256, 2) void pam_pre(
    const float* __restrict__ x, const float* __restrict__ qw,
    const float* __restrict__ kw, const float* __restrict__ vw,
    const float* __restrict__ vb,
    f16* __restrict__ qa, f16* __restrict__ ka, f16* __restrict__ va,
    float* __restrict__ gz)
{
  __shared__ alignas(16) f16 xt[32 * 72];   // xt[n][c] f16, row stride 72 elems
  const int tid = threadIdx.x;
  const int b = blockIdx.x >> 7;
  const int n0 = (blockIdx.x & 127) << 5;
  const int lane = tid & 63;
  const int wv = tid >> 6;
  const int quad = lane >> 4, l15 = lane & 15;

  if (blockIdx.x == 0 && tid < 128) gz[tid] = 0.f;   // gs1|gs2 zero-init

  // stage x[b][c][n0:+32] (fp32) transposed into xt[n][c] (f16)
  {
    const int c = tid >> 2;
    const int j0 = (tid & 3) << 3;
    const float* xp = x + ((size_t)(b * 64 + c) << 12) + n0 + j0;
    const float4 v0 = *(const float4*)xp;
    const float4 v1 = *(const float4*)(xp + 4);
    xt[(j0 + 0) * 72 + c] = f2h(v0.x);
    xt[(j0 + 1) * 72 + c] = f2h(v0.y);
    xt[(j0 + 2) * 72 + c] = f2h(v0.z);
    xt[(j0 + 3) * 72 + c] = f2h(v0.w);
    xt[(j0 + 4) * 72 + c] = f2h(v1.x);
    xt[(j0 + 5) * 72 + c] = f2h(v1.y);
    xt[(j0 + 6) * 72 + c] = f2h(v1.z);
    xt[(j0 + 7) * 72 + c] = f2h(v1.w);
  }
  __syncthreads();

  // conv along channel axis (SAME, zero pad), fp32 math on f16-rounded x
  const float qw0 = qw[0], qw1 = qw[1], qw2 = qw[2];
  const float kw0 = kw[0], kw1 = kw[1], kw2 = kw[2];
  for (int p = 0; p < 8; ++p) {
    const int c = lane;
    const int jr = (p << 2) + wv;
    const int n = n0 + jr;
    const float xm = (c > 0) ? (float)xt[jr * 72 + c - 1] : 0.f;
    const float x0 = (float)xt[jr * 72 + c];
    const float xp = (c < 63) ? (float)xt[jr * 72 + c + 1] : 0.f;
    const float qv = (qw0 * xm + qw1 * x0 + qw2 * xp) * LOG2E;  // log2-domain
    const float kv = kw0 * xm + kw1 * x0 + kw2 * xp;
    const size_t off = ((size_t)((b << 12) + n) << 6) + c;
    qa[off] = f2h(qv);
    ka[off] = f2h(kv);
  }

  // v[b][c][n] = vw @ x + vb via mfma 16x16x32 (wave wv -> c rows [16wv,+16))
  {
    const f16x8 a0 = cvt8(vw + (wv * 16 + l15) * 64 + quad * 8);
    const f16x8 a1 = cvt8(vw + (wv * 16 + l15) * 64 + quad * 8 + 32);
    f32x4 acc[2];
    for (int st = 0; st < 2; ++st) {
      const f16x8 b0 = *(const f16x8*)&xt[(st * 16 + l15) * 72 + quad * 8];
      const f16x8 b1 = *(const f16x8*)&xt[(st * 16 + l15) * 72 + quad * 8 + 32];
      f32x4 z = {0.f, 0.f, 0.f, 0.f};
      z = __builtin_amdgcn_mfma_f32_16x16x32_f16(a0, b0, z, 0, 0, 0);
      acc[st] = __builtin_amdgcn_mfma_f32_16x16x32_f16(a1, b1, z, 0, 0, 0);
    }
    const int cobase = wv * 16 + quad * 4;
    for (int st = 0; st < 2; ++st)
      for (int r = 0; r < 4; ++r) {
        const int co = cobase + r;
        const float val = acc[st][r] + vb[co];
        va[((size_t)(b * 64 + co) << 12) + n0 + st * 16 + l15] = f2h(val);
      }
  }
}

// ---------------------------------------------------------------------------
// attention: block = (b, 32 queries), 512 threads = 8 waves key-split
// (32 keys/wave over 256-key tiles, 16 iters). SINGLE PASS, online softmax,
// 1-deep register prefetch. Grid 512 -> 2 blocks/CU = 16 waves/CU = 4/SIMD.
// __launch_bounds__(512, 2): r10 post-mortem — (512,4) made the backend
// target 8 waves/SIMD (VGPR=64) and spill the loop state to scratch
// (FETCH 5->149 MB, WRITE 4->38 MB). Loose bound restores natural ~80-100
// VGPR allocation (r9 precedent) with zero spill; 2 blocks/CU still fit.
// ---------------------------------------------------------------------------
__global__ __launch_bounds__(512, 2) void pam_attn(
    const f16* __restrict__ qa, const f16* __restrict__ ka,
    const f16* __restrict__ va, const float* __restrict__ gam,
    float* __restrict__ y0, float* __restrict__ gs1, float* __restrict__ gs2)
{
  __shared__ alignas(16) f16 pbuf[8][32 * 32];  // per-wave P, 64B rows, swizzled
  __shared__ float ldsO[32 * 65];
  __shared__ float ldsL[8][32];
  __shared__ float ldsM[8][32];
  __shared__ float ldsMg[32];
  __shared__ float ldsInv[32];

  const int tid = threadIdx.x;
  const int wv = tid >> 6, lane = tid & 63;
  const int quad = lane >> 4, l15 = lane & 15;
  const int b = blockIdx.x & 3;
  const int qt_idx = blockIdx.x >> 2;          // 0..127
  const int qb0 = qt_idx << 5;
  const int phase = qt_idx & 15;               // anti-convoy rotation (16 tiles)

  for (int i = tid; i < 32 * 65; i += 512) ldsO[i] = 0.f;

  const int bn = b << 12;
  f16x8 bq[2][2];
  for (int qt = 0; qt < 2; ++qt) {
    const int q = qb0 + qt * 16 + l15;
    const f16* qp = qa + ((size_t)(bn + q) << 6) + quad * 8;
    bq[qt][0] = *(const f16x8*)qp;
    bq[qt][1] = *(const f16x8*)(qp + 32);
  }

  f32x4 o[2][4] = {};
  float m[2] = {-1e30f, -1e30f};
  float lpart[2] = {0.f, 0.f};
  f16* pb = pbuf[wv];

  // preload iteration 0 K/V fragments (256-key tiles, wave owns 32)
  f16x8 ak[2][2], bv[4];
  {
    const int kb = (phase << 8) + wv * 32;
    for (int mt = 0; mt < 2; ++mt) {
      const f16* kp = ka + ((size_t)(bn + kb + mt * 16 + l15) << 6) + quad * 8;
      ak[mt][0] = *(const f16x8*)kp;
      ak[mt][1] = *(const f16x8*)(kp + 32);
    }
    for (int ct = 0; ct < 4; ++ct)
      bv[ct] = *(const f16x8*)(va + ((size_t)(b * 64 + ct * 16 + l15) << 12) + kb + quad * 8);
  }

#pragma unroll 1
  for (int kt = 0; kt < 16; ++kt) {
    // prefetch next iteration's K/V into separate regs (wraps at 16)
    f16x8 akn[2][2], bvn[4];
    {
      const int kb2 = ((((kt + 1) + phase) & 15) << 8) + wv * 32;
      for (int mt = 0; mt < 2; ++mt) {
        const f16* kp = ka + ((size_t)(bn + kb2 + mt * 16 + l15) << 6) + quad * 8;
        akn[mt][0] = *(const f16x8*)kp;
        akn[mt][1] = *(const f16x8*)(kp + 32);
      }
      for (int ct = 0; ct < 4; ++ct)
        bvn[ct] = *(const f16x8*)(va + ((size_t)(b * 64 + ct * 16 + l15) << 12) + kb2 + quad * 8);
    }

    // S^T = K_slice * Q^T (C=0); online max/rescale; P -> LDS; PV
    for (int qt = 0; qt < 2; ++qt) {
      f32x4 s[2];
      for (int mt = 0; mt < 2; ++mt) {
        f32x4 z = {0.f, 0.f, 0.f, 0.f};
        z = __builtin_amdgcn_mfma_f32_16x16x32_f16(ak[mt][0], bq[qt][0], z, 0, 0, 0);
        s[mt] = __builtin_amdgcn_mfma_f32_16x16x32_f16(ak[mt][1], bq[qt][1], z, 0, 0, 0);
      }
      // tile max for this query (col=l15) across this wave's 32 keys
      float tmax = fmaxf(fmaxf(fmaxf(s[0][0], s[0][1]), fmaxf(s[0][2], s[0][3])),
                         fmaxf(fmaxf(s[1][0], s[1][1]), fmaxf(s[1][2], s[1][3])));
      tmax = fmaxf(tmax, __shfl_xor(tmax, 16, 64));
      tmax = fmaxf(tmax, __shfl_xor(tmax, 32, 64));
      const float mnew = fmaxf(m[qt], tmax);
      const float alpha = fexp2(m[qt] - mnew);   // (l15 = query) layout, quad-uniform
      m[qt] = mnew;

      // P = exp2(S - mnew); update per-lane partial l; pack -> LDS (swizzled)
      const int rowq = qt * 16 + l15;
      char* rowp = (char*)pb + rowq * 64;
      const int sw = rowq & 3;
      float tsum = 0.f;
      for (int mt = 0; mt < 2; ++mt) {
        const float p0 = fexp2(s[mt][0] - mnew);
        const float p1 = fexp2(s[mt][1] - mnew);
        const float p2 = fexp2(s[mt][2] - mnew);
        const float p3 = fexp2(s[mt][3] - mnew);
        tsum += (p0 + p1) + (p2 + p3);
        union { f16 h[4]; uint2 u; } pk;
        pk.h[0] = f2h(p0); pk.h[1] = f2h(p1);
        pk.h[2] = f2h(p2); pk.h[3] = f2h(p3);
        const int cc = (2 * mt + (quad >> 1)) ^ sw;
        *(uint2*)(rowp + cc * 16 + (quad & 1) * 8) = pk.u;
      }
      lpart[qt] = lpart[qt] * alpha + tsum;   // per-lane partial (8 keys/lane)

      // rescale o: o-queries are quad*4+r -> fetch alpha from lane (quad<<4)|(quad*4+r)
      const int srcbase = (lane & 48) + ((lane >> 4) << 2);
      for (int r = 0; r < 4; ++r) {
        const float ar = __shfl(alpha, srcbase + r, 64);
        for (int ct = 0; ct < 4; ++ct) o[qt][ct][r] *= ar;
      }
    }
    __builtin_amdgcn_s_waitcnt(0xC07F);  // lgkmcnt(0): per-wave P writes visible

    // O += P * V
    for (int qt = 0; qt < 2; ++qt) {
      const int rowq = qt * 16 + l15;
      const f16x8 ap =
          *(const f16x8*)((const char*)pb + rowq * 64 + ((quad ^ (rowq & 3)) << 4));
      for (int ct = 0; ct < 4; ++ct)
        o[qt][ct] = __builtin_amdgcn_mfma_f32_16x16x32_f16(ap, bv[ct], o[qt][ct], 0, 0, 0);
    }

    for (int mt = 0; mt < 2; ++mt) { ak[mt][0] = akn[mt][0]; ak[mt][1] = akn[mt][1]; }
    for (int ct = 0; ct < 4; ++ct) bv[ct] = bvn[ct];
  }

  // publish per-wave online state: m quad-uniform; lpart reduced across quads
  for (int qt = 0; qt < 2; ++qt) {
    float v = lpart[qt];
    v += __shfl_xor(v, 16, 64);
    v += __shfl_xor(v, 32, 64);
    if (quad == 0) {
      ldsM[wv][qt * 16 + l15] = m[qt];
      ldsL[wv][qt * 16 + l15] = v;
    }
  }
  __syncthreads();  // ldsM/ldsL published; ldsO zero-init complete

  // global (per-block) max + denom per query
  if (tid < 32) {
    const int q = tid;
    float M = ldsM[0][q];
    for (int w = 1; w < 8; ++w) M = fmaxf(M, ldsM[w][q]);
    float lt = 0.f;
    for (int w = 0; w < 8; ++w) lt += ldsL[w][q] * fexp2(ldsM[w][q] - M);
    ldsMg[q] = M;
    ldsInv[q] = 1.f / lt;
  }
  __syncthreads();

  // m-aware merge of partial O across the 8 key-split waves
  for (int qt = 0; qt < 2; ++qt) {
    for (int r = 0; r < 4; ++r) {
      const int q = qt * 16 + quad * 4 + r;
      const float sc = fexp2(ldsM[wv][q] - ldsMg[q]);
      for (int ct = 0; ct < 4; ++ct)
        atomicAdd(&ldsO[q * 65 + ct * 16 + l15], o[qt][ct][r] * sc);
    }
  }
  __syncthreads();

  // epilogue: y0[b][c][n] = gamma * O / l ; BN partial sums
  // thread -> (c = tid>>3, 4 consecutive q starting at (tid&7)*4)
  const float g = gam[0];
  {
    const int c = tid >> 3;
    const int q0 = (tid & 7) << 2;
    float4 v4;
    float* vp = &v4.x;
    float s1 = 0.f, s2 = 0.f;
    for (int r = 0; r < 4; ++r) {
      const float val = g * ldsO[(q0 + r) * 65 + c] * ldsInv[q0 + r];
      vp[r] = val; s1 += val; s2 += val * val;
    }
    *(float4*)(y0 + ((size_t)(b * 64 + c) << 12) + qb0 + q0) = v4;
    s1 += __shfl_xor(s1, 1, 64);
    s2 += __shfl_xor(s2, 1, 64);
    s1 += __shfl_xor(s1, 2, 64);
    s2 += __shfl_xor(s2, 2, 64);
    s1 += __shfl_xor(s1, 4, 64);
    s2 += __shfl_xor(s2, 4, 64);
    if ((tid & 7) == 0) {
      atomicAdd(&gs1[c], s1);
      atomicAdd(&gs2[c], s2);
    }
  }
}

// ---------------------------------------------------------------------------
// apply: BN(scale/shift recomputed per block from gs1/gs2) + residual.
// ---------------------------------------------------------------------------
__global__ __launch_bounds__(256, 2) void pam_apply(
    const float* __restrict__ y0, const float* __restrict__ x,
    const float* __restrict__ gs1, const float* __restrict__ gs2,
    const float* __restrict__ bnw, const float* __restrict__ bnb,
    float* __restrict__ out)
{
  const int i = (blockIdx.x * 256 + threadIdx.x) << 2;   // 4 elems/thread
  const int c = (i >> 12) & 63;
  const float inv_n = 1.f / 16384.f;
  const float mean = gs1[c] * inv_n;
  const float var = fmaxf(gs2[c] * inv_n - mean * mean, 0.f);
  const float sc = bnw[c] * rsqrtf(var + 1e-5f);
  const float sh = bnb[c] - mean * sc;
  const float4 y = *(const float4*)(y0 + i);
  const float4 xv = *(const float4*)(x + i);
  float4 r;
  r.x = y.x * sc + sh + xv.x;
  r.y = y.y * sc + sh + xv.y;
  r.z = y.z * sc + sh + xv.z;
  r.w = y.w * sc + sh + xv.w;
  *(float4*)(out + i) = r;
}

// ---------------------------------------------------------------------------
extern "C" void kernel_launch(void* const* d_in, const int* in_sizes, int n_in,
                              void* d_out, int out_size, void* d_ws, size_t ws_size,
                              hipStream_t stream)
{
  (void)in_sizes; (void)n_in; (void)out_size; (void)ws_size;
  const float* x   = (const float*)d_in[0];
  const float* qw  = (const float*)d_in[1];
  const float* kw  = (const float*)d_in[2];
  const float* vw  = (const float*)d_in[3];
  const float* vb  = (const float*)d_in[4];
  const float* gam = (const float*)d_in[5];
  const float* bnw = (const float*)d_in[6];
  const float* bnb = (const float*)d_in[7];

  char* ws = (char*)d_ws;
  f16*   qa  = (f16*)(ws);
  f16*   ka  = (f16*)(ws + (2u << 20));
  f16*   va  = (f16*)(ws + (4u << 20));
  float* y0  = (float*)(ws + (6u << 20));
  float* gs1 = (float*)(ws + (10u << 20));          // 64 floats
  float* gs2 = (float*)(ws + (10u << 20) + 256);    // 64 floats (contiguous)

  pam_pre  <<<512, 256, 0, stream>>>(x, qw, kw, vw, vb, qa, ka, va, gs1);
  pam_attn <<<512, 512, 0, stream>>>(qa, ka, va, gam, y0, gs1, gs2);
  pam_apply<<<1024, 256, 0, stream>>>(y0, x, gs1, gs2, bnw, bnb, (float*)d_out);
}

// Round 12
// 161.744 us; speedup vs baseline: 1.4702x; 1.2553x over previous
//
#include <hip/hip_runtime.h>
#include <stdint.h>

using f16 = _Float16;

typedef _Float16 f16x8 __attribute__((ext_vector_type(8)));
typedef float f32x4 __attribute__((ext_vector_type(4)));

#define LOG2E 1.44269504088896340736f

__device__ __forceinline__ f16 f2h(float f) { return (f16)f; }  // RNE

#if __has_builtin(__builtin_amdgcn_exp2f)
__device__ __forceinline__ float fexp2(float x) { return __builtin_amdgcn_exp2f(x); }
#else
__device__ __forceinline__ float fexp2(float x) { return exp2f(x); }
#endif

__device__ __forceinline__ f16x8 cvt8(const float* p) {
  const float4 a = *(const float4*)p;
  const float4 b = *(const float4*)(p + 4);
  f16x8 r;
  r[0] = (f16)a.x; r[1] = (f16)a.y; r[2] = (f16)a.z; r[3] = (f16)a.w;
  r[4] = (f16)b.x; r[5] = (f16)b.y; r[6] = (f16)b.z; r[7] = (f16)b.w;
  return r;
}

// B=4, C=64, N=4096.  Global in/out FP32; internal tensor-core path FP16.
// ws layout (bytes):
//   0     qa  f16 [4][4096][64]      (2 MB)  q*log2e, position-major
//   2 MB  ka2 f16 [4][8][4096][8]    (2 MB)  K channel-chunked: [b][c8][key][8c]
//   4 MB  va2 f16 [4][512][64][8]    (2 MB)  V key-chunked:     [b][k8][c][8k]
//   6 MB  y0  f32 [4][64][4096]      (4 MB)  gamma*attn_out, pre-BN
//   10 MB stats: gs1[64] | gs2[64]   (zeroed by pre block 0)

// ---------------------------------------------------------------------------
// pre: conv1d q/k over channels, v = vw@x+vb via MFMA.
// grid 512 = (b, n-tile of 32), 256 threads. Block 0 zeroes gs1/gs2.
// ---------------------------------------------------------------------------
__global__ __launch_bounds__(256, 2) void pam_pre(
    const float* __restrict__ x, const float* __restrict__ qw,
    const float* __restrict__ kw, const float* __restrict__ vw,
    const float* __restrict__ vb,
    f16* __restrict__ qa, f16* __restrict__ ka2, f16* __restrict__ va2,
    float* __restrict__ gz)
{
  __shared__ alignas(16) f16 xt[32 * 72];   // xt[n][c] f16, row stride 72
  const int tid = threadIdx.x;
  const int b = blockIdx.x >> 7;
  const int n0 = (blockIdx.x & 127) << 5;
  const int lane = tid & 63;
  const int wv = tid >> 6;
  const int quad = lane >> 4, l15 = lane & 15;

  if (blockIdx.x == 0 && tid < 128) gz[tid] = 0.f;   // gs1|gs2 zero-init

  // stage x[b][c][n0:+32] (fp32) transposed into xt[n][c] (f16)
  {
    const int c = tid >> 2;
    const int j0 = (tid & 3) << 3;
    const float* xp = x + ((size_t)(b * 64 + c) << 12) + n0 + j0;
    const float4 v0 = *(const float4*)xp;
    const float4 v1 = *(const float4*)(xp + 4);
    xt[(j0 + 0) * 72 + c] = f2h(v0.x);
    xt[(j0 + 1) * 72 + c] = f2h(v0.y);
    xt[(j0 + 2) * 72 + c] = f2h(v0.z);
    xt[(j0 + 3) * 72 + c] = f2h(v0.w);
    xt[(j0 + 4) * 72 + c] = f2h(v1.x);
    xt[(j0 + 5) * 72 + c] = f2h(v1.y);
    xt[(j0 + 6) * 72 + c] = f2h(v1.z);
    xt[(j0 + 7) * 72 + c] = f2h(v1.w);
  }
  __syncthreads();

  // conv over channel axis (SAME, zero pad)
  const float qw0 = qw[0], qw1 = qw[1], qw2 = qw[2];
  const float kw0 = kw[0], kw1 = kw[1], kw2 = kw[2];
  for (int p = 0; p < 8; ++p) {
    const int c = lane;
    const int jr = (p << 2) + wv;
    const int n = n0 + jr;
    const float xm = (c > 0) ? (float)xt[jr * 72 + c - 1] : 0.f;
    const float x0 = (float)xt[jr * 72 + c];
    const float xp = (c < 63) ? (float)xt[jr * 72 + c + 1] : 0.f;
    const float qv = (qw0 * xm + qw1 * x0 + qw2 * xp) * LOG2E;  // log2-domain
    const float kv = kw0 * xm + kw1 * x0 + kw2 * xp;
    qa[((size_t)((b << 12) + n) << 6) + c] = f2h(qv);
    // ka2[b][c>>3][n][c&7]
    ka2[((size_t)(b * 8 + (c >> 3)) << 15) + (n << 3) + (c & 7)] = f2h(kv);
  }

  // v[c][n] = vw @ x + vb via mfma (wave wv -> c rows [16wv,+16))
  {
    const f16x8 a0 = cvt8(vw + (wv * 16 + l15) * 64 + quad * 8);
    const f16x8 a1 = cvt8(vw + (wv * 16 + l15) * 64 + quad * 8 + 32);
    f32x4 acc[2];
    for (int st = 0; st < 2; ++st) {
      const f16x8 b0 = *(const f16x8*)&xt[(st * 16 + l15) * 72 + quad * 8];
      const f16x8 b1 = *(const f16x8*)&xt[(st * 16 + l15) * 72 + quad * 8 + 32];
      f32x4 z = {0.f, 0.f, 0.f, 0.f};
      z = __builtin_amdgcn_mfma_f32_16x16x32_f16(a0, b0, z, 0, 0, 0);
      acc[st] = __builtin_amdgcn_mfma_f32_16x16x32_f16(a1, b1, z, 0, 0, 0);
    }
    const int cobase = wv * 16 + quad * 4;
    for (int st = 0; st < 2; ++st)
      for (int r = 0; r < 4; ++r) {
        const int co = cobase + r;
        const int n = n0 + st * 16 + l15;
        const float val = acc[st][r] + vb[co];
        // va2[b][n>>3][co][n&7]
        va2[((size_t)(b * 512 + (n >> 3)) << 9) + (co << 3) + (n & 7)] = f2h(val);
      }
  }
}

// ---------------------------------------------------------------------------
// attention v12: ONE 1024-thread block per CU (grid 256) -> 16 waves/CU
// co-resident BY CONSTRUCTION. Block = (b, 64 queries); wave (qt=wv&3,
// ks=wv>>2): q-tile qt vs key-slice ks. 32 iters of 128-key tiles; K/V tiles
// staged cooperatively into double-buffered LDS (each byte used by 4 waves;
// traffic halved vs r9). Staging: register relay, contiguous 16 B/lane from
// chunked ka2/va2 layouts; LDS chunk layouts give 2-way (free) bank access
// for both staging writes and fragment reads, no padding needed.
// Online softmax per wave; 4-way m-aware merge per q-tile.
// ---------------------------------------------------------------------------
__global__ __launch_bounds__(1024) void pam_attn(
    const f16* __restrict__ qa, const f16* __restrict__ ka2,
    const f16* __restrict__ va2, const float* __restrict__ gam,
    float* __restrict__ y0, float* __restrict__ gs1, float* __restrict__ gs2)
{
  __shared__ alignas(16) f16 kbuf[2][8192];    // [c8][key][8c] 16 KB per buf
  __shared__ alignas(16) f16 vbuf[2][8192];    // [k8][c][8k]  16 KB per buf
  __shared__ alignas(16) f16 pbuf[16][512];    // per-wave P: 16q x 32k, swizzled
  __shared__ float ldsO[64 * 65];
  __shared__ float ldsM[4][64], ldsL[4][64], ldsMg[64], ldsInv[64];

  const int tid = threadIdx.x;
  const int wv = tid >> 6, lane = tid & 63;
  const int quad = lane >> 4, l15 = lane & 15;
  const int qt = wv & 3, ks = wv >> 2;
  const int b = blockIdx.x & 3;
  const int qb = blockIdx.x >> 2;          // 0..63
  const int qb0 = qb << 6;
  const int phase = qb & 31;               // anti-convoy rotation

  for (int i = tid; i < 64 * 65; i += 1024) ldsO[i] = 0.f;

  const int bn = b << 12;
  // Q fragments for this wave's q-tile
  f16x8 bq0, bq1;
  {
    const int q = qb0 + qt * 16 + l15;
    const f16* qp = qa + ((size_t)(bn + q) << 6) + quad * 8;
    bq0 = *(const f16x8*)qp;
    bq1 = *(const f16x8*)(qp + 32);
  }

  // staging source pointers (contiguous 16 B per lane by construction)
  const int k_c8 = tid >> 7, k_key = tid & 127;
  const f16* kg0 = ka2 + (((size_t)(b * 8 + k_c8)) << 15) + (k_key << 3);
  const int v_kc = tid >> 6, v_c = tid & 63;
  const f16* vg0 = va2 + (((size_t)(b * 512 + v_kc)) << 9) + (v_c << 3);

  // fragment read bases (f16 element offsets in a 16 KB buffer)
  const int ak_base = (((quad << 7) + ks * 32 + l15) << 3);       // +half*4096 +mt*128
  const int bv_base = (((((ks << 2) + quad) << 6) + l15) << 3);   // +ct*128

  f32x4 o[4] = {};
  float m = -1e30f, lp = 0.f;
  f16* pb = pbuf[wv];
  const int sw = l15 & 3;

  // stage tile 'phase' into buf 0
  {
    const f16x8 kr = *(const f16x8*)(kg0 + ((size_t)phase << 10));
    const f16x8 vr = *(const f16x8*)(vg0 + ((size_t)phase << 13));
    *(f16x8*)(kbuf[0] + (tid << 3)) = kr;
    *(f16x8*)(vbuf[0] + (tid << 3)) = vr;
  }
  __syncthreads();

#pragma unroll 1
  for (int kt = 0; kt < 32; ++kt) {
    const int cur = kt & 1;
    // issue next tile's global loads (consumed by ds_write at loop end)
    const int tn = (kt + 1 + phase) & 31;
    const f16x8 krn = *(const f16x8*)(kg0 + ((size_t)tn << 10));
    const f16x8 vrn = *(const f16x8*)(vg0 + ((size_t)tn << 13));

    const f16* kc_ = kbuf[cur];
    const f16* vc_ = vbuf[cur];
    const f16x8 ak00 = *(const f16x8*)(kc_ + ak_base);
    const f16x8 ak01 = *(const f16x8*)(kc_ + ak_base + 4096);
    const f16x8 ak10 = *(const f16x8*)(kc_ + ak_base + 128);
    const f16x8 ak11 = *(const f16x8*)(kc_ + ak_base + 128 + 4096);
    f16x8 bv[4];
    for (int ct = 0; ct < 4; ++ct)
      bv[ct] = *(const f16x8*)(vc_ + bv_base + ct * 128);

    // S^T[key][q] for this wave's 32 keys
    f32x4 s0, s1;
    {
      f32x4 z = {0.f, 0.f, 0.f, 0.f};
      z = __builtin_amdgcn_mfma_f32_16x16x32_f16(ak00, bq0, z, 0, 0, 0);
      s0 = __builtin_amdgcn_mfma_f32_16x16x32_f16(ak01, bq1, z, 0, 0, 0);
    }
    {
      f32x4 z = {0.f, 0.f, 0.f, 0.f};
      z = __builtin_amdgcn_mfma_f32_16x16x32_f16(ak10, bq0, z, 0, 0, 0);
      s1 = __builtin_amdgcn_mfma_f32_16x16x32_f16(ak11, bq1, z, 0, 0, 0);
    }

    // online softmax: tile max across 32 keys for query l15 (cross-quad)
    float tmax = fmaxf(fmaxf(fmaxf(s0[0], s0[1]), fmaxf(s0[2], s0[3])),
                       fmaxf(fmaxf(s1[0], s1[1]), fmaxf(s1[2], s1[3])));
    tmax = fmaxf(tmax, __shfl_xor(tmax, 16, 64));
    tmax = fmaxf(tmax, __shfl_xor(tmax, 32, 64));
    const float mnew = fmaxf(m, tmax);
    const float alpha = fexp2(m - mnew);   // quad-uniform at l15=q
    m = mnew;

    // P = exp2(S - m); per-lane partial l; pack 4 keys -> b64 swizzled write
    char* rowp = (char*)pb + l15 * 64;
    float tsum = 0.f;
    {
      const float p0 = fexp2(s0[0] - mnew);
      const float p1 = fexp2(s0[1] - mnew);
      const float p2 = fexp2(s0[2] - mnew);
      const float p3 = fexp2(s0[3] - mnew);
      tsum += (p0 + p1) + (p2 + p3);
      union { f16 h[4]; uint2 u; } pk;
      pk.h[0] = f2h(p0); pk.h[1] = f2h(p1);
      pk.h[2] = f2h(p2); pk.h[3] = f2h(p3);
      const int cc = (quad >> 1) ^ sw;
      *(uint2*)(rowp + cc * 16 + (quad & 1) * 8) = pk.u;
    }
    {
      const float p0 = fexp2(s1[0] - mnew);
      const float p1 = fexp2(s1[1] - mnew);
      const float p2 = fexp2(s1[2] - mnew);
      const float p3 = fexp2(s1[3] - mnew);
      tsum += (p0 + p1) + (p2 + p3);
      union { f16 h[4]; uint2 u; } pk;
      pk.h[0] = f2h(p0); pk.h[1] = f2h(p1);
      pk.h[2] = f2h(p2); pk.h[3] = f2h(p3);
      const int cc = (2 + (quad >> 1)) ^ sw;
      *(uint2*)(rowp + cc * 16 + (quad & 1) * 8) = pk.u;
    }
    lp = lp * alpha + tsum;

    // rescale o (rows q=quad*4+r): alpha lives at lane (quad<<4)|(quad*4+r)
    const int srcbase = (lane & 48) + ((lane >> 4) << 2);
    for (int r = 0; r < 4; ++r) {
      const float ar = __shfl(alpha, srcbase + r, 64);
      for (int ct = 0; ct < 4; ++ct) o[ct][r] *= ar;
    }
    __builtin_amdgcn_s_waitcnt(0xC07F);  // lgkmcnt(0): P visible to own wave

    const f16x8 ap =
        *(const f16x8*)((const char*)pb + l15 * 64 + ((quad ^ sw) << 4));
    for (int ct = 0; ct < 4; ++ct)
      o[ct] = __builtin_amdgcn_mfma_f32_16x16x32_f16(ap, bv[ct], o[ct], 0, 0, 0);

    // write next tile into the other buffer (compiler waits vmcnt here)
    *(f16x8*)(kbuf[cur ^ 1] + (tid << 3)) = krn;
    *(f16x8*)(vbuf[cur ^ 1] + (tid << 3)) = vrn;
    __syncthreads();   // staging visible + buffer handoff
  }

  // publish per-wave online state (m quad-uniform; lp reduced across quads)
  {
    float v = lp;
    v += __shfl_xor(v, 16, 64);
    v += __shfl_xor(v, 32, 64);
    if (quad == 0) {
      ldsM[ks][qt * 16 + l15] = m;
      ldsL[ks][qt * 16 + l15] = v;
    }
  }
  __syncthreads();

  // per-query global max + denom
  if (tid < 64) {
    const float M = fmaxf(fmaxf(ldsM[0][tid], ldsM[1][tid]),
                          fmaxf(ldsM[2][tid], ldsM[3][tid]));
    const float lt = ldsL[0][tid] * fexp2(ldsM[0][tid] - M) +
                     ldsL[1][tid] * fexp2(ldsM[1][tid] - M) +
                     ldsL[2][tid] * fexp2(ldsM[2][tid] - M) +
                     ldsL[3][tid] * fexp2(ldsM[3][tid] - M);
    ldsMg[tid] = M;
    ldsInv[tid] = 1.f / lt;
  }
  __syncthreads();

  // m-aware 4-way merge of partial O
  for (int r = 0; r < 4; ++r) {
    const int q = qt * 16 + quad * 4 + r;
    const float sc = fexp2(ldsM[ks][q] - ldsMg[q]);
    for (int ct = 0; ct < 4; ++ct)
      atomicAdd(&ldsO[q * 65 + ct * 16 + l15], o[ct][r] * sc);
  }
  __syncthreads();

  // epilogue: y0[b][c][n] = gamma * O / l ; BN partial sums
  const float g = gam[0];
  {
    const int c = tid >> 4;              // 0..63 (uniform per quad)
    const int q0 = (tid & 15) << 2;      // 0..60
    float4 v4;
    float* vp = &v4.x;
    float s1 = 0.f, s2 = 0.f;
    for (int r = 0; r < 4; ++r) {
      const float val = g * ldsO[(q0 + r) * 65 + c] * ldsInv[q0 + r];
      vp[r] = val; s1 += val; s2 += val * val;
    }
    *(float4*)(y0 + ((size_t)(b * 64 + c) << 12) + qb0 + q0) = v4;
    s1 += __shfl_xor(s1, 1, 64);
    s2 += __shfl_xor(s2, 1, 64);
    s1 += __shfl_xor(s1, 2, 64);
    s2 += __shfl_xor(s2, 2, 64);
    s1 += __shfl_xor(s1, 4, 64);
    s2 += __shfl_xor(s2, 4, 64);
    s1 += __shfl_xor(s1, 8, 64);
    s2 += __shfl_xor(s2, 8, 64);
    if (l15 == 0) {
      atomicAdd(&gs1[c], s1);
      atomicAdd(&gs2[c], s2);
    }
  }
}

// ---------------------------------------------------------------------------
// apply: BN(scale/shift from gs1/gs2) + residual.
// ---------------------------------------------------------------------------
__global__ __launch_bounds__(256, 2) void pam_apply(
    const float* __restrict__ y0, const float* __restrict__ x,
    const float* __restrict__ gs1, const float* __restrict__ gs2,
    const float* __restrict__ bnw, const float* __restrict__ bnb,
    float* __restrict__ out)
{
  const int i = (blockIdx.x * 256 + threadIdx.x) << 2;   // 4 elems/thread
  const int c = (i >> 12) & 63;
  const float inv_n = 1.f / 16384.f;
  const float mean = gs1[c] * inv_n;
  const float var = fmaxf(gs2[c] * inv_n - mean * mean, 0.f);
  const float sc = bnw[c] * rsqrtf(var + 1e-5f);
  const float sh = bnb[c] - mean * sc;
  const float4 y = *(const float4*)(y0 + i);
  const float4 xv = *(const float4*)(x + i);
  float4 r;
  r.x = y.x * sc + sh + xv.x;
  r.y = y.y * sc + sh + xv.y;
  r.z = y.z * sc + sh + xv.z;
  r.w = y.w * sc + sh + xv.w;
  *(float4*)(out + i) = r;
}

// ---------------------------------------------------------------------------
extern "C" void kernel_launch(void* const* d_in, const int* in_sizes, int n_in,
                              void* d_out, int out_size, void* d_ws, size_t ws_size,
                              hipStream_t stream)
{
  (void)in_sizes; (void)n_in; (void)out_size; (void)ws_size;
  const float* x   = (const float*)d_in[0];
  const float* qw  = (const float*)d_in[1];
  const float* kw  = (const float*)d_in[2];
  const float* vw  = (const float*)d_in[3];
  const float* vb  = (const float*)d_in[4];
  const float* gam = (const float*)d_in[5];
  const float* bnw = (const float*)d_in[6];
  const float* bnb = (const float*)d_in[7];

  char* ws = (char*)d_ws;
  f16*   qa  = (f16*)(ws);
  f16*   ka2 = (f16*)(ws + (2u << 20));
  f16*   va2 = (f16*)(ws + (4u << 20));
  float* y0  = (float*)(ws + (6u << 20));
  float* gs1 = (float*)(ws + (10u << 20));          // 64 floats
  float* gs2 = (float*)(ws + (10u << 20) + 256);    // 64 floats (contiguous)

  pam_pre  <<<512, 256, 0, stream>>>(x, qw, kw, vw, vb, qa, ka2, va2, gs1);
  pam_attn <<<256, 1024, 0, stream>>>(qa, ka2, va2, gam, y0, gs1, gs2);
  pam_apply<<<1024, 256, 0, stream>>>(y0, x, gs1, gs2, bnw, bnb, (float*)d_out);
}